// Round 7
// baseline (128.001 us; speedup 1.0000x reference)
//
#include <hip/hip_runtime.h>

// Point-transformer block. R20 = R19 with two cuts in the hot path:
// (a) masked-A chained MFMA: 8 A-frags where rows 4u+c hold pos_w2[.][c]
//     masked to k-chunk u (zero elsewhere). Chaining 8 MFMAs over the
//     256-wide k=(u,h) space per s-pack makes lane(q,j) reg r = e(t=4s+q,
//     j, c=r) directly: removes ALL 48 cndmask selects and the 16
//     read-after-MFMA stall points of R19. Masked rows add exact 0.0 to the
//     f32 C-chain and live chunks accumulate in R19's order: bit-identical.
// (b) phase-1b pw1/pb1 loads vectorized to float4 (64 scalar VMEM -> 16).
// Everything else identical to R19 (4 waves/block, (256,6), two-half 2b).

typedef _Float16 h2 __attribute__((ext_vector_type(2)));
typedef _Float16 h8 __attribute__((ext_vector_type(8)));
typedef float f32x4 __attribute__((ext_vector_type(4)));

#define AH_STRIDE 36    // a-table row stride in dwords (32 data + 4 pad)
#define MW1_OFF  256    // ws offset: mw1 pairs, [24][48] dwords
#define MW2_OFF 1408    // ws offset: mw2 pairs, [24][48] dwords
#define AW2T_OFF 2560   // ws offset: masked MFMA A-frag table, [8 chunks][64 lanes][4 dwords]

union H8U { h8 v; h2 p[4]; unsigned u[4]; };

__device__ __forceinline__ h2 pkrtz(float a, float b) {
    return __builtin_bit_cast(h2, __builtin_amdgcn_cvt_pkrtz(a, b));
}
__device__ __forceinline__ h2 uash2(unsigned u) {
    return __builtin_bit_cast(h2, u);
}
__device__ __forceinline__ h2 hmax2(h2 a, h2 b) {
    return __builtin_elementwise_max(a, b);   // v_pk_max_f16
}

#if __has_builtin(__builtin_amdgcn_fdot2)
__device__ __forceinline__ float dot2acc(h2 a, h2 b, float c) {
    return __builtin_amdgcn_fdot2(a, b, c, false);
}
#else
__device__ __forceinline__ float dot2acc(h2 a, h2 b, float c) {
    float d;
    asm("v_dot2_f32_f16 %0, %1, %2, %3"
        : "=v"(d)
        : "v"(__builtin_bit_cast(int, a)), "v"(__builtin_bit_cast(int, b)), "v"(c));
    return d;
}
#endif

// sum across the 16-lane DPP row via row_ror 1,2,4,8 (all lanes get total)
__device__ __forceinline__ float dpp_add16(float x) {
    float s = x;
    int t;
    t = __builtin_amdgcn_update_dpp(0, __builtin_bit_cast(int, s), 0x121, 0xf, 0xf, false);
    s += __builtin_bit_cast(float, t);
    t = __builtin_amdgcn_update_dpp(0, __builtin_bit_cast(int, s), 0x122, 0xf, 0xf, false);
    s += __builtin_bit_cast(float, t);
    t = __builtin_amdgcn_update_dpp(0, __builtin_bit_cast(int, s), 0x124, 0xf, 0xf, false);
    s += __builtin_bit_cast(float, t);
    t = __builtin_amdgcn_update_dpp(0, __builtin_bit_cast(int, s), 0x128, 0xf, 0xf, false);
    s += __builtin_bit_cast(float, t);
    return s;
}

// ---- pre-kernel: pack f16-pair weight tables into workspace ----
__global__ void wpack(const float* __restrict__ pw2, const float* __restrict__ aw1,
                      const float* __restrict__ ab1, const float* __restrict__ aw2,
                      const float* __restrict__ mw1, const float* __restrict__ mw2,
                      unsigned* __restrict__ ws) {
    const int t = threadIdx.x;
    const float L2E = 1.44269504f;
    if (blockIdx.x == 0) {
        if (t < 96) {
            const int hp = t & 31, c = t >> 5;
            ws[c*32+hp] = __builtin_bit_cast(unsigned, pkrtz(pw2[(2*hp)*3+c], pw2[(2*hp+1)*3+c]));
        } else if (t < 114) {
            const int idx = t - 96, r = idx / 6, gp = idx % 6;
            ws[96+r*6+gp] = __builtin_bit_cast(unsigned, pkrtz(aw1[r*12+2*gp], aw1[r*12+2*gp+1]));
        } else if (t < 120) {
            const int gp = t - 114;
            ws[114+gp] = __builtin_bit_cast(unsigned, pkrtz(ab1[2*gp], ab1[2*gp+1]));
        } else if (t < 138) {
            const int idx = t - 120, gp = idx / 3, c = idx % 3;
            ws[120+gp*3+c] = __builtin_bit_cast(unsigned,
                pkrtz(aw2[(2*gp)*3+c] * L2E, aw2[(2*gp+1)*3+c] * L2E));
        }
    }
    const int idx = blockIdx.x * 256 + t;
    // mw1/mw2 pair tables: 1152 entries each
    if (idx < 1152) {
        const int cp = idx / 48, o = idx % 48;
        ws[MW1_OFF + idx] = __builtin_bit_cast(unsigned,
            pkrtz(mw1[(2*cp)*48+o], mw1[(2*cp+1)*48+o]));
        ws[MW2_OFF + idx] = __builtin_bit_cast(unsigned,
            pkrtz(mw2[(2*cp)*48+o], mw2[(2*cp+1)*48+o]));
    }
    // Masked MFMA A-frag table, 8 chunks of K=32 spanning k=(u,h) in [0,256):
    //   global k = 32*m + k_local, u' = k>>6, h = k&63
    //   A[row=4u+c][k] = (c<3 && u==u') ? pos_w2[h][c] : 0
    // lane l holds A[l&15][k_local=(l>>4)*8 + e], e=0..7, as f16 pairs:
    //   ws[AW2T_OFF + m*256 + l*4 + d] = (k_local=2d, k_local=2d+1)
    if (idx < 2048) {
        const int m = idx >> 8, rem = idx & 255;
        const int l = rem >> 2, d = rem & 3;
        const int row = l & 15, c = row & 3, u = row >> 2;
        const int kloc = ((l >> 4) * 8) + 2*d;
        const int kg = 32*m + kloc;
        const int up = kg >> 6, h = kg & 63;
        const bool valid = (c < 3) && (u == up);
        const float v0 = valid ? pw2[h*3 + c] : 0.0f;
        const float v1 = valid ? pw2[(h+1)*3 + c] : 0.0f;
        ws[AW2T_OFF + idx] = __builtin_bit_cast(unsigned, pkrtz(v0, v1));
    }
}

struct SmWave {
    float q4[64], k4[64], v4[64];      // 768 B
    float sa[48], h1[48];              // 384 B
    unsigned a1h[16 * AH_STRIDE];      // 2304 B
    unsigned a2h[16 * AH_STRIDE];      // 2304 B
};                                     // 5760 B/wave, 16B-aligned members

__global__ __launch_bounds__(256, 6) void pt_main(
    const float* __restrict__ data,     // (BG, 16, 3)
    const float* __restrict__ wqkv,     // (3, 9)
    const float* __restrict__ pw1,      // (3, 64)
    const float* __restrict__ pb1,      // (64)
    const float* __restrict__ pb2,      // (3)
    const float* __restrict__ ab2,      // (3)
    const float* __restrict__ mb1,      // (48)
    const float* __restrict__ mb2,      // (48)
    const float* __restrict__ mw3,      // (48, 1)
    const float* __restrict__ mb3,      // (1)
    const unsigned* __restrict__ wsp,   // packed f16-pair weights
    float* __restrict__ out)            // (BG)
{
    __shared__ __attribute__((aligned(16))) SmWave sm[4];

    const int tid = threadIdx.x;
    const int w   = tid >> 6;           // wave id within block
    const int ln  = tid & 63;           // lane within wave
    const int g   = blockIdx.x * 4 + w; // group handled by this wave
    SmWave& S = sm[w];

    // single data[] load for both phase-1 stages (same point p for 1a & 1b)
    const int p  = ln & 15;
    const float x0 = data[g*48 + p*3 + 0];
    const float x1 = data[g*48 + p*3 + 1];
    const float x2 = data[g*48 + p*3 + 2];

    // ---- phase 1a: qkv (lanes 0..47), stride-4 layout ----
    if (ln < 48) {
        const int sec = ln >> 4;
        float* dst = (sec == 0) ? S.q4 : (sec == 1) ? S.k4 : S.v4;
        #pragma unroll
        for (int c = 0; c < 3; ++c) {
            dst[p*4+c] = fmaf(x0, wqkv[0*9 + sec*3 + c],
                         fmaf(x1, wqkv[1*9 + sec*3 + c],
                         x2 * wqkv[2*9 + sec*3 + c]));
        }
        dst[p*4+3] = 0.0f;
    }

    // ---- phase 1b: a-tables. lane -> point p, 16 hiddens at (ln>>4)*16 ----
    {
        const int qd = ln >> 4;
        const int hc = qd << 4;
        float s[16];
        #pragma unroll
        for (int wv = 0; wv < 4; ++wv) {
            const float4 r0 = *(const float4*)&pw1[hc + 4*wv];
            const float4 r1 = *(const float4*)&pw1[64 + hc + 4*wv];
            const float4 r2 = *(const float4*)&pw1[128 + hc + 4*wv];
            #pragma unroll
            for (int cc = 0; cc < 4; ++cc) {
                const int c = wv*4 + cc;
                s[c] = fmaf(x0, (&r0.x)[cc], fmaf(x1, (&r1.x)[cc], x2 * (&r2.x)[cc]));
            }
        }
        const float4 b0 = *(const float4*)&pb1[hc];
        const float4 b1 = *(const float4*)&pb1[hc + 4];
        const float4 b2 = *(const float4*)&pb1[hc + 8];
        const float4 b3 = *(const float4*)&pb1[hc + 12];
        float bb[16];
        #pragma unroll
        for (int cc = 0; cc < 4; ++cc) {
            bb[cc]    = (&b0.x)[cc];
            bb[4+cc]  = (&b1.x)[cc];
            bb[8+cc]  = (&b2.x)[cc];
            bb[12+cc] = (&b3.x)[cc];
        }
        uint4 a1u0, a1u1, a2u0, a2u1;
        #pragma unroll
        for (int d = 0; d < 4; ++d) {
            const int c = d * 2;
            (&a1u0.x)[d] = __builtin_bit_cast(unsigned, pkrtz(s[c]   + bb[c],   s[c+1] + bb[c+1]));
            (&a1u1.x)[d] = __builtin_bit_cast(unsigned, pkrtz(s[8+c] + bb[8+c], s[9+c] + bb[9+c]));
            (&a2u0.x)[d] = __builtin_bit_cast(unsigned, pkrtz(s[c],   s[c+1]));
            (&a2u1.x)[d] = __builtin_bit_cast(unsigned, pkrtz(s[8+c], s[9+c]));
        }
        const int base = p * AH_STRIDE + (qd << 3);
        *(uint4*)&S.a1h[base]     = a1u0;
        *(uint4*)&S.a1h[base + 4] = a1u1;
        *(uint4*)&S.a2h[base]     = a2u0;
        *(uint4*)&S.a2h[base + 4] = a2u1;
    }
    __builtin_amdgcn_wave_barrier();   // order DS writes before phase-2 reads

    // ---- phase 2: j = ln&15, q = ln>>4; lane owns pairs (i = q+4s, j) ----
    const int j = p, q = ln >> 4;
    const float4 kv = *(const float4*)&S.k4[j*4];
    const float4 vv = *(const float4*)&S.v4[j*4];
    const h2 z2 = {(_Float16)0, (_Float16)0};
    const float L2E = 1.44269504f;
    const float mb_0 = ab2[0] * L2E, mb_1 = ab2[1] * L2E, mb_2 = ab2[2] * L2E;

    // ---- phase 2a: rel-emb projection via masked-A chained MFMA ----
    // this lane's a2 k-slices (h = 8q..8q+7 and 32+8q..32+8q+7)
    H8U b2c0, b2c1;
    b2c0.v = *(const h8*)&S.a2h[j * AH_STRIDE + q*4];
    b2c1.v = *(const h8*)&S.a2h[j * AH_STRIDE + q*4 + 16];

    const f32x4 pb2v = {pb2[0], pb2[1], pb2[2], 0.0f};
    const unsigned* afb = wsp + AW2T_OFF + ln*4;   // per-lane A-frag base

    float e[4][3];
    #pragma unroll
    for (int s = 0; s < 4; ++s) {
        f32x4 acc = pb2v;
        #pragma unroll
        for (int tt = 0; tt < 4; ++tt) {
            const int t = 4*s + tt;
            H8U r0, r1, d0, d1, afa, afc;
            r0.v = *(const h8*)&S.a1h[t * AH_STRIDE + q*4];
            r1.v = *(const h8*)&S.a1h[t * AH_STRIDE + q*4 + 16];
            *(uint4*)&afa = *(const uint4*)&afb[(2*tt)   * 256];
            *(uint4*)&afc = *(const uint4*)&afb[(2*tt+1) * 256];
            #pragma unroll
            for (int m = 0; m < 4; ++m) {
                d0.p[m] = hmax2(r0.p[m] - b2c0.p[m], z2);
                d1.p[m] = hmax2(r1.p[m] - b2c1.p[m], z2);
            }
            // rows 4u+c of afa/afc are zero unless u==tt: other lanes' rows
            // pass C through exactly (0.0 contribution) -> bit-identical.
            acc = __builtin_amdgcn_mfma_f32_16x16x32_f16(afa.v, d0.v, acc, 0, 0, 0);
            acc = __builtin_amdgcn_mfma_f32_16x16x32_f16(afc.v, d1.v, acc, 0, 0, 0);
        }
        e[s][0] = acc[0]; e[s][1] = acc[1]; e[s][2] = acc[2];
    }

    // ---- phase 2b: attn-MLP + softmax, two halves (proven R13 dataflow) ----
    #pragma unroll
    for (int half = 0; half < 2; ++half) {
        const int iA = q + 8*half, iB = iA + 4;
        const int ha = 2*half, hb = 2*half + 1;

        const float eA0 = e[ha][0], eA1 = e[ha][1], eA2 = e[ha][2];
        const float eB0 = e[hb][0], eB1 = e[hb][1], eB2 = e[hb][2];

        const float4 qA = *(const float4*)&S.q4[iA*4];
        const float4 qB = *(const float4*)&S.q4[iB*4];

        const float viA0 = vv.x + eA0, viA1 = vv.y + eA1, viA2 = vv.z + eA2;
        const float viB0 = vv.x + eB0, viB1 = vv.y + eB1, viB2 = vv.z + eB2;
        const float siA0 = qA.x - kv.x + eA0, siA1 = qA.y - kv.y + eA1, siA2 = qA.z - kv.z + eA2;
        const float siB0 = qB.x - kv.x + eB0, siB1 = qB.y - kv.y + eB1, siB2 = qB.z - kv.z + eB2;

        // attn-MLP in packed f16, both pairs (aw2/ab2 pre-scaled by L2E)
        const h2 sAx = pkrtz(siA0, siA0), sAy = pkrtz(siA1, siA1), sAz = pkrtz(siA2, siA2);
        const h2 sBx = pkrtz(siB0, siB0), sBy = pkrtz(siB1, siB1), sBz = pkrtz(siB2, siB2);
        float mA0 = mb_0, mA1 = mb_1, mA2 = mb_2;
        float mB0 = mb_0, mB1 = mb_1, mB2 = mb_2;
        #pragma unroll
        for (int gp = 0; gp < 6; ++gp) {
            const h2 b1p = uash2(wsp[114+gp]);
            const h2 u0 = uash2(wsp[96+0*6+gp]);
            const h2 u1 = uash2(wsp[96+1*6+gp]);
            const h2 u2 = uash2(wsp[96+2*6+gp]);
            const h2 v0 = uash2(wsp[120+gp*3+0]);
            const h2 v1 = uash2(wsp[120+gp*3+1]);
            const h2 v2 = uash2(wsp[120+gp*3+2]);
            h2 accA = b1p, accB = b1p;
            accA = __builtin_elementwise_fma(sAx, u0, accA);
            accA = __builtin_elementwise_fma(sAy, u1, accA);
            accA = __builtin_elementwise_fma(sAz, u2, accA);
            accB = __builtin_elementwise_fma(sBx, u0, accB);
            accB = __builtin_elementwise_fma(sBy, u1, accB);
            accB = __builtin_elementwise_fma(sBz, u2, accB);
            h2 hA = hmax2(accA, z2), hB = hmax2(accB, z2);
            mA0 = dot2acc(hA, v0, mA0);
            mA1 = dot2acc(hA, v1, mA1);
            mA2 = dot2acc(hA, v2, mA2);
            mB0 = dot2acc(hB, v0, mB0);
            mB1 = dot2acc(hB, v1, mB1);
            mB2 = dot2acc(hB, v2, mB2);
        }

        // softmax over j (DPP row sums; exponents already in log2 domain)
        const float pA0 = __builtin_amdgcn_exp2f(mA0);
        const float pA1 = __builtin_amdgcn_exp2f(mA1);
        const float pA2 = __builtin_amdgcn_exp2f(mA2);
        const float pB0 = __builtin_amdgcn_exp2f(mB0);
        const float pB1 = __builtin_amdgcn_exp2f(mB1);
        const float pB2 = __builtin_amdgcn_exp2f(mB2);

        const float nA0 = dpp_add16(pA0 * viA0);
        const float nA1 = dpp_add16(pA1 * viA1);
        const float nA2 = dpp_add16(pA2 * viA2);
        const float dA0 = dpp_add16(pA0);
        const float dA1 = dpp_add16(pA1);
        const float dA2 = dpp_add16(pA2);
        const float nB0 = dpp_add16(pB0 * viB0);
        const float nB1 = dpp_add16(pB1 * viB1);
        const float nB2 = dpp_add16(pB2 * viB2);
        const float dB0 = dpp_add16(pB0);
        const float dB1 = dpp_add16(pB1);
        const float dB2 = dpp_add16(pB2);

        if (j == 0) {
            S.sa[iA*3+0] = nA0 * __builtin_amdgcn_rcpf(dA0);
            S.sa[iA*3+1] = nA1 * __builtin_amdgcn_rcpf(dA1);
            S.sa[iA*3+2] = nA2 * __builtin_amdgcn_rcpf(dA2);
            S.sa[iB*3+0] = nB0 * __builtin_amdgcn_rcpf(dB0);
            S.sa[iB*3+1] = nB1 * __builtin_amdgcn_rcpf(dB1);
            S.sa[iB*3+2] = nB2 * __builtin_amdgcn_rcpf(dB2);
        }
    }
    __builtin_amdgcn_wave_barrier();   // s_sa writes before tail reads

    // ---- phase 3: MLP 48->48->48->1 (lanes 0..47), f16-pair weights ----
    if (ln < 48) {
        const int o = ln;
        float a0 = 0.f, a1 = 0.f;
        #pragma unroll
        for (int c = 0; c < 48; c += 4) {
            const float4 sa = *(const float4*)&S.sa[c];   // broadcast read
            const h2 pa = pkrtz(sa.x, sa.y);
            const h2 pb = pkrtz(sa.z, sa.w);
            a0 = dot2acc(pa, uash2(wsp[MW1_OFF + (c>>1)*48 + o]), a0);
            a1 = dot2acc(pb, uash2(wsp[MW1_OFF + ((c>>1)+1)*48 + o]), a1);
        }
        S.h1[o] = fmaxf(a0 + a1 + mb1[o], 0.0f);
        __builtin_amdgcn_wave_barrier();   // same-wave LDS handoff
        float b0 = 0.f, b1 = 0.f;
        #pragma unroll
        for (int c = 0; c < 48; c += 4) {
            const float4 hh = *(const float4*)&S.h1[c];
            const h2 pa = pkrtz(hh.x, hh.y);
            const h2 pb = pkrtz(hh.z, hh.w);
            b0 = dot2acc(pa, uash2(wsp[MW2_OFF + (c>>1)*48 + o]), b0);
            b1 = dot2acc(pb, uash2(wsp[MW2_OFF + ((c>>1)+1)*48 + o]), b1);
        }
        const float h2v = fmaxf(b0 + b1 + mb2[o], 0.0f);
        const float fv = h2v * mw3[o];
        const float r = dpp_add16(fv);     // row sums in lanes 0,16,32
        const int ri = __builtin_bit_cast(int, r);
        const float tot =
            __builtin_bit_cast(float, __builtin_amdgcn_readlane(ri, 0)) +
            __builtin_bit_cast(float, __builtin_amdgcn_readlane(ri, 16)) +
            __builtin_bit_cast(float, __builtin_amdgcn_readlane(ri, 32));
        if (o == 0) out[g] = tot + mb3[0];
    }
}

extern "C" void kernel_launch(void* const* d_in, const int* in_sizes, int n_in,
                              void* d_out, int out_size, void* d_ws, size_t ws_size,
                              hipStream_t stream) {
    const float* data = (const float*)d_in[1];
    unsigned* ws = (unsigned*)d_ws;
    const int groups = out_size;  // B*G = 16384

    wpack<<<8, 256, 0, stream>>>(
        (const float*)d_in[5],   // pw2
        (const float*)d_in[7],   // aw1
        (const float*)d_in[8],   // ab1
        (const float*)d_in[9],   // aw2
        (const float*)d_in[11],  // mw1
        (const float*)d_in[13],  // mw2
        ws);

    pt_main<<<groups / 4, 256, 0, stream>>>(
        data,
        (const float*)d_in[2],   // wqkv
        (const float*)d_in[3],   // pw1
        (const float*)d_in[4],   // pb1
        (const float*)d_in[6],   // pb2
        (const float*)d_in[10],  // ab2
        (const float*)d_in[12],  // mb1
        (const float*)d_in[14],  // mb2
        (const float*)d_in[15],  // mw3
        (const float*)d_in[16],  // mb3
        ws,
        (float*)d_out);
}